// Round 1
// baseline (947.496 us; speedup 1.0000x reference)
//
#include <hip/hip_runtime.h>
#include <hip/hip_bf16.h>
#include <cstdint>

// ---------------------------------------------------------------------------
// Decoder LSTM (teacher-forced), MI355X.
// Plan:
//   1. cvt_bf16: W_out, W_ih, W_hh fp32 -> bf16 (in ws)
//   2. gather_embed: X[b*T+t] = bf16(relu(emb[tok])), tok = [BOS, target[:-1]]; zero flags
//   3. gemm_bt: G0 = X @ W_ih^T + b_ih + b_hh   (fp32, stored in d_out scratch region)
//   4. lstm_rec: 16 blocks, W_hh slice resident in LDS, MFMA per step,
//      cross-block h exchange via Hs + device-scope flags
//   5. gemm_bt: logits = Hs @ W_out^T + b_out -> d_out  (overwrites G0 scratch)
// ---------------------------------------------------------------------------

#define V_ 32000
#define H_ 512
#define B_ 16
#define T_ 128

typedef __attribute__((ext_vector_type(8))) short s16x8;
typedef __attribute__((ext_vector_type(4))) float f32x4;

typedef unsigned int __attribute__((address_space(1))) as1_u32;
typedef unsigned int __attribute__((address_space(3))) as3_u32;

__device__ __forceinline__ void async_cp16(const void* g, void* l) {
  __builtin_amdgcn_global_load_lds((const as1_u32*)g, (as3_u32*)l, 16, 0, 0);
}

__device__ __forceinline__ short f2bf(float f) {
  union { float f; unsigned u; } v; v.f = f;
  unsigned r = v.u + 0x7fffu + ((v.u >> 16) & 1u);   // RNE, inputs finite
  return (short)(r >> 16);
}

// ---------------------------------------------------------------------------
__global__ void cvt_bf16(const float* __restrict__ in, short* __restrict__ out, int n4) {
  int i = blockIdx.x * blockDim.x + threadIdx.x;
  if (i >= n4) return;
  float4 v = ((const float4*)in)[i];
  short4 o;
  o.x = f2bf(v.x); o.y = f2bf(v.y); o.z = f2bf(v.z); o.w = f2bf(v.w);
  ((short4*)out)[i] = o;
}

// grid 2048 blocks (one per (b,t)), 128 threads
__global__ void gather_embed(const float* __restrict__ emb, const int* __restrict__ tgt,
                             short* __restrict__ X, int* __restrict__ flags) {
  int m = blockIdx.x;
  int b = m >> 7, t = m & 127;
  int tok = (t == 0) ? 1 : tgt[b * T_ + t - 1];       // BOS = 1
  int k = threadIdx.x * 4;
  float4 v = *(const float4*)&emb[(size_t)tok * H_ + k];
  short4 o;
  o.x = f2bf(fmaxf(v.x, 0.f)); o.y = f2bf(fmaxf(v.y, 0.f));
  o.z = f2bf(fmaxf(v.z, 0.f)); o.w = f2bf(fmaxf(v.w, 0.f));
  *(short4*)&X[(size_t)m * H_ + k] = o;
  if (m == 0) flags[threadIdx.x] = 0;                 // 128 step flags
}

// ---------------------------------------------------------------------------
// C = A(MxK bf16) @ B(NxK bf16)^T + bias ; 128x128 tile, BK=64, 4 waves,
// XOR-swizzled LDS chunks (16B chunk c at slot c^(r&7)) -> conflict-free b128.
__global__ __launch_bounds__(256, 2) void gemm_bt(
    const short* __restrict__ A, const short* __restrict__ B,
    const float* __restrict__ bias0, const float* __restrict__ bias1,
    float* __restrict__ out, int M, int N, int K, int ldo)
{
  __shared__ short As[1024 * 8];   // 128 rows x 8 chunks x 16B = 16KB
  __shared__ short Bs[1024 * 8];
  const int tid = threadIdx.x;
  const int wave = tid >> 6, lane = tid & 63;
  const int row0 = blockIdx.y * 128, col0 = blockIdx.x * 128;
  const int m_in = lane & 15, quad = lane >> 4;
  const int wm = (wave >> 1) * 64, wn = (wave & 1) * 64;
  f32x4 acc[4][4] = {};
  for (int kt = 0; kt < K; kt += 64) {
    for (int i = 0; i < 4; ++i) {
      int s = (i * 4 + wave) * 64 + lane;            // chunk slot 0..1023
      int r = s >> 3, cs = s & 7, cd = cs ^ (r & 7);
      async_cp16(A + ((size_t)(row0 + r) * K + kt + cd * 8), &As[s * 8]);
      async_cp16(B + ((size_t)(col0 + r) * K + kt + cd * 8), &Bs[s * 8]);
    }
    __syncthreads();                                  // compiler drains vmcnt
    for (int kk = 0; kk < 2; ++kk) {
      s16x8 af[4], bfr[4];
      int c = kk * 4 + quad;
      for (int i = 0; i < 4; ++i) {
        int ra = wm + i * 16 + m_in;
        af[i] = *(const s16x8*)&As[(ra * 8 + (c ^ (ra & 7))) * 8];
        int rb = wn + i * 16 + m_in;
        bfr[i] = *(const s16x8*)&Bs[(rb * 8 + (c ^ (rb & 7))) * 8];
      }
      for (int i = 0; i < 4; ++i)
        for (int j = 0; j < 4; ++j)
          acc[i][j] = __builtin_amdgcn_mfma_f32_16x16x32_bf16(af[i], bfr[j], acc[i][j], 0, 0, 0);
    }
    __syncthreads();
  }
  for (int j = 0; j < 4; ++j) {
    int n = col0 + wn + j * 16 + m_in;
    float bs = bias0[n] + (bias1 ? bias1[n] : 0.f);
    for (int i = 0; i < 4; ++i) {
      int mrow = row0 + wm + i * 16 + quad * 4;      // D: col=lane&15, row=quad*4+reg
      f32x4 a = acc[i][j];
      for (int p = 0; p < 4; ++p)
        out[(size_t)(mrow + p) * ldo + n] = a[p] + bs;
    }
  }
}

// ---------------------------------------------------------------------------
// Recurrence: 16 blocks x 512 threads. Block s owns hidden slice [s*32, s*32+32)
// => 128 W_hh rows (4 gates x 32), resident in LDS (128KB bf16, swizzled).
// Per step: MFMA 16x128x512, fp32 gate math (c in regs), h exchange via Hs(bf16)
// + device-scope flag barrier.
__global__ __launch_bounds__(512, 1) void lstm_rec(
    const float* __restrict__ G0,    // [B*T][2048] fp32 (in d_out scratch)
    const short* __restrict__ Whh,   // [2048][512] bf16
    const float* __restrict__ h0, const float* __restrict__ c0,
    short* __restrict__ Hs,          // [B*T][512] bf16 (exchange + GEMM2 A)
    int* flags,
    float* __restrict__ hcf)         // d_out + B*T*V : hf[B*H] then cf[B*H]
{
  __shared__ short Wl[8192 * 8];     // 128 rows x 64 chunks x 16B = 128KB
  __shared__ short hl[1024 * 8];     // 16 rows  x 64 chunks x 16B = 16KB
  __shared__ float gl[128 * 17];     // gates [unit_local][batch], pad 17

  const int S = blockIdx.x;
  const int tid = threadIdx.x, wave = tid >> 6, lane = tid & 63;
  const int nin = lane & 15, quad = lane >> 4;

  // Stage W slice (once). Local row r -> global unit (r/32)*512 + S*32 + (r%32).
  for (int i = tid; i < 8192; i += 512) {
    int r = i >> 6, cs = i & 63, cd = cs ^ (r & 7);
    int u = (r >> 5) * 512 + S * 32 + (r & 31);
    *(int4*)&Wl[i * 8] = *(const int4*)&Whh[(size_t)u * H_ + cd * 8];
  }
  const int batch = tid >> 5, hid = tid & 31;
  float c_reg = c0[batch * H_ + S * 32 + hid];
  __syncthreads();

  for (int tt = 0; tt < T_; ++tt) {
    if (tt > 0) {
      if (tid == 0) {
        while (__hip_atomic_load(&flags[tt - 1], __ATOMIC_RELAXED, __HIP_MEMORY_SCOPE_AGENT) < 16) {}
        __threadfence();             // acquire: invalidate L1/L2 before reading Hs
      }
      __syncthreads();
    }
    // Stage h (16 batches x 512) into hl, swizzled.
    for (int i = tid; i < 1024; i += 512) {
      int m = i >> 6, cs = i & 63, cd = cs ^ (m & 7);
      if (tt == 0) {
        const float* hp = &h0[m * H_ + cd * 8];
        float4 v0 = *(const float4*)hp, v1 = *(const float4*)(hp + 4);
        s16x8 o;
        o[0] = f2bf(v0.x); o[1] = f2bf(v0.y); o[2] = f2bf(v0.z); o[3] = f2bf(v0.w);
        o[4] = f2bf(v1.x); o[5] = f2bf(v1.y); o[6] = f2bf(v1.z); o[7] = f2bf(v1.w);
        *(s16x8*)&hl[i * 8] = o;
      } else {
        *(int4*)&hl[i * 8] = *(const int4*)&Hs[((size_t)m * T_ + tt - 1) * H_ + cd * 8];
      }
    }
    __syncthreads();
    // MFMA: wave w computes units [w*16, w*16+16) x 16 batches over K=512.
    f32x4 acc = {};
    {
      int r = wave * 16 + nin;
      for (int ks = 0; ks < 16; ++ks) {
        int c = ks * 4 + quad;
        s16x8 af = *(const s16x8*)&hl[(nin * 64 + (c ^ (nin & 7))) * 8];
        s16x8 bf = *(const s16x8*)&Wl[(r * 64 + (c ^ (r & 7))) * 8];
        acc = __builtin_amdgcn_mfma_f32_16x16x32_bf16(af, bf, acc, 0, 0, 0);
      }
      int u = wave * 16 + nin;
      for (int p = 0; p < 4; ++p)
        gl[u * 17 + quad * 4 + p] = acc[p];          // D: col=unit, row=batch
    }
    __syncthreads();
    // Pointwise gates (fp32), one (batch, hid) per thread.
    {
      size_t gbase = ((size_t)batch * T_ + tt) * 2048 + S * 32 + hid;
      float xi = G0[gbase         ] + gl[(0 * 32 + hid) * 17 + batch];
      float xf = G0[gbase +  512  ] + gl[(1 * 32 + hid) * 17 + batch];
      float xg = G0[gbase + 1024  ] + gl[(2 * 32 + hid) * 17 + batch];
      float xo = G0[gbase + 1536  ] + gl[(3 * 32 + hid) * 17 + batch];
      float si = 1.f / (1.f + __expf(-xi));
      float sf = 1.f / (1.f + __expf(-xf));
      float so = 1.f / (1.f + __expf(-xo));
      c_reg = sf * c_reg + si * tanhf(xg);
      float hn = so * tanhf(c_reg);
      Hs[((size_t)batch * T_ + tt) * H_ + S * 32 + hid] = f2bf(hn);
      if (tt == T_ - 1) {
        hcf[(size_t)batch * H_ + S * 32 + hid] = hn;
        hcf[B_ * H_ + (size_t)batch * H_ + S * 32 + hid] = c_reg;
      }
    }
    __syncthreads();                 // all stores drained (vmcnt) before release
    if (tid == 0) {
      __threadfence();               // release: write back L2
      __hip_atomic_fetch_add(&flags[tt], 1, __ATOMIC_RELAXED, __HIP_MEMORY_SCOPE_AGENT);
    }
  }
}

// ---------------------------------------------------------------------------
extern "C" void kernel_launch(void* const* d_in, const int* in_sizes, int n_in,
                              void* d_out, int out_size, void* d_ws, size_t ws_size,
                              hipStream_t stream) {
  (void)in_sizes; (void)n_in; (void)out_size; (void)ws_size;
  const float* h0   = (const float*)d_in[1];
  const float* c0   = (const float*)d_in[2];
  const int*   tgt  = (const int*)d_in[3];
  const float* emb  = (const float*)d_in[4];
  const float* Wih  = (const float*)d_in[5];
  const float* Whh  = (const float*)d_in[6];
  const float* bih  = (const float*)d_in[7];
  const float* bhh  = (const float*)d_in[8];
  const float* Wout = (const float*)d_in[9];
  const float* bout = (const float*)d_in[10];
  float* out = (float*)d_out;

  char* ws = (char*)d_ws;
  short* wsWout = (short*)(ws);                 // 32,768,000 B
  short* wsWih  = (short*)(ws + 32768000);      //  2,097,152 B
  short* wsWhh  = (short*)(ws + 34865152);      //  2,097,152 B
  short* wsX    = (short*)(ws + 36962304);      //  2,097,152 B
  short* wsHs   = (short*)(ws + 39059456);      //  2,097,152 B
  int*   flags  = (int*)  (ws + 41156608);      //        512 B

  cvt_bf16<<<16000, 256, 0, stream>>>(Wout, wsWout, 4096000);
  cvt_bf16<<<1024, 256, 0, stream>>>(Wih, wsWih, 262144);
  cvt_bf16<<<1024, 256, 0, stream>>>(Whh, wsWhh, 262144);
  gather_embed<<<2048, 128, 0, stream>>>(emb, tgt, wsX, flags);
  // G0 -> d_out scratch region (overwritten later by logits GEMM)
  gemm_bt<<<dim3(16, 16), 256, 0, stream>>>(wsX, wsWih, bih, bhh, out, 2048, 2048, 512, 2048);
  lstm_rec<<<16, 512, 0, stream>>>(out, wsWhh, h0, c0, wsHs, flags, out + (size_t)B_ * T_ * V_);
  gemm_bt<<<dim3(250, 16), 256, 0, stream>>>(wsHs, wsWout, bout, nullptr, out, 2048, 32000, 512, 32000);
}